// Round 10
// baseline (339.185 us; speedup 1.0000x reference)
//
#include <hip/hip_runtime.h>
#include <math.h>

#define DIM      256
#define L_SEQ    1024
#define B_SZ     8
#define D_INNER  512
#define D_STATE  16
#define DT_RANK  16
#define N_TOK    (B_SZ * L_SEQ)   // 8192
#define T_CH     64
#define CL       256              // scan chunk length

typedef unsigned short u16;
typedef __attribute__((ext_vector_type(4))) float f32x4;
typedef __attribute__((ext_vector_type(8))) short short8;
struct __align__(8) us4 { u16 x, y, z, w; };

// ---- workspace float offsets (93.7 MB, verified no overlapping live buffers) ----
#define OFF_WB   0                     // bf16 weights                  (  471,040)
#define OFF_XT   471040                // fp32 8192x256 token-major x   (2,097,152)
#define OFF_XNB  2568192               // bf16 8192x256 LN out          (1,048,576)
#define OFF_XZ   3616768               // fp32 8192x1024 xz             (8,388,608)
#define OFF_XC   12005376              // fp32 8192x512 u               (4,194,304)
#define OFF_DBL  16199680              // fp32 8192x48                  (  393,216)
#define OFF_DT   16592896              // fp32 8192x512 dt              (4,194,304)
#define OFF_YB   20787200              // bf16 8192x512 y -> 2,097,152 floats (FIXED size)
#define OFF_HE   22884352              // fp32 8x4x512x16               (  262,144)
#define OFF_HI   23146496              // fp32 8x4x512x16               (  262,144)
#define OFF_CD   23408640              // fp32 8x4x512                  (   16,384)
// end = 23,425,024 floats = 93.7 MB
// aliases onto dead regions:
#define OFF_XF2  OFF_XC                // XC=u dead after scan_fix
#define OFF_TOUT (OFF_XC + 2097152)
#define OFF_H    OFF_XZ                // XZ dead after scan_fix
// WB sub-offsets in u16 elements
#define WB_IN    0
#define WB_OUT   262144
#define WB_W1    393216
#define WB_W2    655360
#define WB_XP    917504

__device__ __forceinline__ u16 f2b(float f) {
    unsigned int u = __float_as_uint(f);
    return (u16)((u + 0x7fffu + ((u >> 16) & 1u)) >> 16);   // RNE
}
__device__ __forceinline__ float b2f(u16 v) {
    return __uint_as_float(((unsigned)v) << 16);
}

// ---------------- weight fp32->bf16 convert (5 segments) ----------------
__global__ __launch_bounds__(256) void cvt5_kernel(const float* __restrict__ a,
                                                   const float* __restrict__ b,
                                                   const float* __restrict__ c,
                                                   const float* __restrict__ d,
                                                   const float* __restrict__ e,
                                                   u16* __restrict__ out) {
    int i = blockIdx.x * 256 + threadIdx.x;   // total 942080
    const float* src; int off;
    if (i < 262144)      { src = a; off = i; }
    else if (i < 393216) { src = b; off = i - 262144; }
    else if (i < 655360) { src = c; off = i - 393216; }
    else if (i < 917504) { src = d; off = i - 655360; }
    else                 { src = e; off = i - 917504; }
    out[i] = f2b(src[off]);
}

// ---------------- transpose in: x (8,256,1024) -> XT (8192,256) ----------------
__global__ __launch_bounds__(256) void tin_kernel(const float* __restrict__ x,
                                                  float* __restrict__ XT) {
    __shared__ float tile[64][65];
    int bb = blockIdx.x >> 6, c0 = ((blockIdx.x >> 4) & 3) << 6, l0 = (blockIdx.x & 15) << 6;
    int tr = threadIdx.x >> 6, tc = threadIdx.x & 63;
    const float* src = x + ((size_t)bb * 256 + c0) * 1024 + l0;
    #pragma unroll
    for (int i = 0; i < 16; i++) tile[tr + i * 4][tc] = src[(size_t)(tr + i * 4) * 1024 + tc];
    __syncthreads();
    float* dst = XT + ((size_t)bb * 1024 + l0) * 256 + c0;
    #pragma unroll
    for (int i = 0; i < 16; i++) dst[(size_t)(tr + i * 4) * 256 + tc] = tile[tc][tr + i * 4];
}

// ---------------- transpose out: TOUT (8192,256) -> out (8,256,1024) ----------------
__global__ __launch_bounds__(256) void tout_kernel(const float* __restrict__ T,
                                                   float* __restrict__ outp) {
    __shared__ float tile[64][65];
    int bb = blockIdx.x >> 6, c0 = ((blockIdx.x >> 4) & 3) << 6, l0 = (blockIdx.x & 15) << 6;
    int tr = threadIdx.x >> 6, tc = threadIdx.x & 63;
    const float* src = T + ((size_t)bb * 1024 + l0) * 256 + c0;
    #pragma unroll
    for (int i = 0; i < 16; i++) tile[tr + i * 4][tc] = src[(size_t)(tr + i * 4) * 256 + tc];
    __syncthreads();
    float* dst = outp + ((size_t)bb * 256 + c0) * 1024 + l0;
    #pragma unroll
    for (int i = 0; i < 16; i++) dst[(size_t)(tr + i * 4) * 1024 + tc] = tile[tc][tr + i * 4];
}

// ---------------- LayerNorm over C=256, one block per token; bf16 out ----------------
__global__ __launch_bounds__(256) void ln_kernel(const float* __restrict__ in,
                                                 const float* __restrict__ g,
                                                 const float* __restrict__ b,
                                                 u16* __restrict__ out) {
    int token = blockIdx.x;
    int c = threadIdx.x;
    float v = in[(size_t)token * DIM + c];
    float s = v, s2 = v * v;
    #pragma unroll
    for (int o = 32; o; o >>= 1) {
        s  += __shfl_down(s, o);
        s2 += __shfl_down(s2, o);
    }
    __shared__ float red[8];
    int w = threadIdx.x >> 6;
    if ((threadIdx.x & 63) == 0) { red[w] = s; red[4 + w] = s2; }
    __syncthreads();
    if (threadIdx.x == 0) {
        float a = 0.f, aa = 0.f;
        for (int i = 0; i < 4; i++) { a += red[i]; aa += red[4 + i]; }
        red[0] = a; red[4] = aa;
    }
    __syncthreads();
    float mean = red[0] * (1.f / DIM);
    float var  = red[4] * (1.f / DIM) - mean * mean;
    float rstd = rsqrtf(var + 1e-5f);
    out[(size_t)token * DIM + c] = f2b((v - mean) * rstd * g[c] + b[c]);
}

// ---------------- global->LDS async helper (16B) ----------------
__device__ __forceinline__ void gload16(const void* g, void* l) {
    __builtin_amdgcn_global_load_lds(
        (const __attribute__((address_space(1))) unsigned int*)g,
        (__attribute__((address_space(3))) unsigned int*)l,
        16, 0, 0);
}

// ---------------- bf16 MFMA GEMM: C[M,N] = A[M,K] @ W[N,K]^T ----------------
template <int EPI>
__global__ __launch_bounds__(256) void gemm_mfma(const u16* __restrict__ A,
                                                 const u16* __restrict__ W,
                                                 void* __restrict__ Cout,
                                                 int M, int N, int K,
                                                 const float* __restrict__ bias,
                                                 const float* __restrict__ extra) {
    __shared__ u16 Als[4096];   // [128][32] bf16
    __shared__ u16 Bls[4096];
    int tid = threadIdx.x;
    int w = tid >> 6, l = tid & 63;
    int m0 = blockIdx.y << 7, n0 = blockIdx.x << 7;

    int srow = tid >> 2;
    int scol = (tid & 3) << 3;
    const u16* Ag  = A + (size_t)(m0 + srow) * K + scol;
    const u16* Ag2 = A + (size_t)(m0 + 64 + srow) * K + scol;
    const u16* Wg  = W + (size_t)(n0 + srow) * K + scol;
    const u16* Wg2 = W + (size_t)(n0 + 64 + srow) * K + scol;
    u16* Ab0 = Als + (w << 9);
    u16* Ab1 = Als + 2048 + (w << 9);
    u16* Bb0 = Bls + (w << 9);
    u16* Bb1 = Bls + 2048 + (w << 9);

    int wr = (w >> 1) << 6, wc = (w & 1) << 6;
    int fr = l & 15, fk = (l >> 4) << 3;

    f32x4 acc[4][4] = {};
    for (int k0 = 0; k0 < K; k0 += 32) {
        gload16(Ag + k0, Ab0);
        gload16(Ag2 + k0, Ab1);
        gload16(Wg + k0, Bb0);
        gload16(Wg2 + k0, Bb1);
        __syncthreads();
        short8 af[4], bfr[4];
        #pragma unroll
        for (int i = 0; i < 4; i++)
            af[i] = *(const short8*)&Als[(wr + i * 16 + fr) * 32 + fk];
        #pragma unroll
        for (int j = 0; j < 4; j++)
            bfr[j] = *(const short8*)&Bls[(wc + j * 16 + fr) * 32 + fk];
        #pragma unroll
        for (int i = 0; i < 4; i++)
            #pragma unroll
            for (int j = 0; j < 4; j++)
                acc[i][j] = __builtin_amdgcn_mfma_f32_16x16x32_bf16(af[i], bfr[j], acc[i][j], 0, 0, 0);
        __syncthreads();
    }

    int cr = (l >> 4) << 2;
    int ccol = l & 15;
    #pragma unroll
    for (int i = 0; i < 4; i++) {
        #pragma unroll
        for (int j = 0; j < 4; j++) {
            int n = n0 + wc + j * 16 + ccol;
            #pragma unroll
            for (int r = 0; r < 4; r++) {
                int m = m0 + wr + i * 16 + cr + r;
                float v = acc[i][j][r];
                if (EPI == 0) {
                    ((float*)Cout)[(size_t)m * N + n] = v;
                } else if (EPI == 1) {
                    ((float*)Cout)[(size_t)m * N + n] = v + extra[(size_t)m * DIM + n];
                } else if (EPI == 2) {
                    v += bias[n];
                    ((u16*)Cout)[(size_t)m * N + n] = f2b(0.5f * v * (1.f + erff(v * 0.70710678118f)));
                } else {
                    v += bias[n] + extra[(size_t)m * DIM + n];
                    ((float*)Cout)[(size_t)m * N + n] = v;
                }
            }
        }
    }
}

// ---------------- depthwise causal conv (k=4) + silu; fp32 out ----------------
__global__ __launch_bounds__(256) void conv_kernel(const float* __restrict__ XZ,
                                                   const float* __restrict__ cw,
                                                   const float* __restrict__ cb,
                                                   float* __restrict__ XC) {
    int idx = blockIdx.x * 256 + threadIdx.x;
    int d = idx & 511;
    int token = idx >> 9;
    int l = token & 1023, b = token >> 10;
    const float* base = XZ + (size_t)b * L_SEQ * 1024 + d;
    float acc = cb[d];
    #pragma unroll
    for (int j = 0; j < 4; j++) {
        int ls = l - 3 + j;
        if (ls >= 0) acc = fmaf(base[(size_t)ls * 1024], cw[d * 4 + j], acc);
    }
    XC[(size_t)token * 512 + d] = acc / (1.f + __expf(-acc));
}

// ---------------- xproj v3b: MFMA x_proj from fp32 XC (in-register cvt) ----------------
__global__ __launch_bounds__(128) void xproj3_kernel(const float* __restrict__ XCf,
                                                     const u16* __restrict__ WXP,
                                                     float* __restrict__ DBL) {
    __shared__ float dbl_s[32][49];
    int tid = threadIdx.x;
    int w = tid >> 6, l = tid & 63;
    int m0 = blockIdx.x << 5;
    int fr = l & 15, fk = (l >> 4) << 3;
    const float* Af = XCf + (size_t)(m0 + (w << 4) + fr) * 512 + fk;
    const u16* Wb = WXP + (size_t)fr * 512 + fk;
    f32x4 acc[3] = {};
    for (int k0 = 0; k0 < 512; k0 += 32) {
        float4 fa = *(const float4*)(Af + k0);
        float4 fb = *(const float4*)(Af + k0 + 4);
        short8 a0;
        a0[0] = (short)f2b(fa.x); a0[1] = (short)f2b(fa.y);
        a0[2] = (short)f2b(fa.z); a0[3] = (short)f2b(fa.w);
        a0[4] = (short)f2b(fb.x); a0[5] = (short)f2b(fb.y);
        a0[6] = (short)f2b(fb.z); a0[7] = (short)f2b(fb.w);
        short8 b0 = *(const short8*)(Wb + k0);
        short8 b1 = *(const short8*)(Wb + 16 * 512 + k0);
        short8 b2 = *(const short8*)(Wb + 32 * 512 + k0);
        acc[0] = __builtin_amdgcn_mfma_f32_16x16x32_bf16(a0, b0, acc[0], 0, 0, 0);
        acc[1] = __builtin_amdgcn_mfma_f32_16x16x32_bf16(a0, b1, acc[1], 0, 0, 0);
        acc[2] = __builtin_amdgcn_mfma_f32_16x16x32_bf16(a0, b2, acc[2], 0, 0, 0);
    }
    int cr = (l >> 4) << 2, ccol = l & 15;
    #pragma unroll
    for (int j = 0; j < 3; j++)
        #pragma unroll
        for (int r = 0; r < 4; r++)
            dbl_s[(w << 4) + cr + r][j * 16 + ccol] = acc[j][r];
    __syncthreads();
    #pragma unroll
    for (int it = 0; it < 3; it++) {
        int fidx = it * 512 + tid * 4;
        int row = fidx / 48, col = fidx % 48;
        float4 v;
        v.x = dbl_s[row][col]; v.y = dbl_s[row][col + 1];
        v.z = dbl_s[row][col + 2]; v.w = dbl_s[row][col + 3];
        *(float4*)(DBL + (size_t)(m0 + row) * 48 + col) = v;
    }
}

// ---------------- dt_proj + softplus ----------------
__global__ __launch_bounds__(256) void dtproj_kernel(const float* __restrict__ DBL,
                                                     const float* __restrict__ wdt,
                                                     const float* __restrict__ wdb,
                                                     float* __restrict__ DT) {
    int idx = blockIdx.x * 256 + threadIdx.x;
    int token = idx >> 7, q = idx & 127;
    int d0 = q << 2;
    const float4* dtr4 = (const float4*)(DBL + (size_t)token * 48);
    float4 t0 = dtr4[0], t1 = dtr4[1], t2 = dtr4[2], t3 = dtr4[3];
    float4 ov;
    #pragma unroll
    for (int qq = 0; qq < 4; qq++) {
        int d = d0 + qq;
        const float4* wr = (const float4*)(wdt + (size_t)d * 16);
        float4 w0 = wr[0], w1 = wr[1], w2 = wr[2], w3 = wr[3];
        float a = wdb[d];
        a += t0.x * w0.x + t0.y * w0.y + t0.z * w0.z + t0.w * w0.w;
        a += t1.x * w1.x + t1.y * w1.y + t1.z * w1.z + t1.w * w1.w;
        a += t2.x * w2.x + t2.y * w2.y + t2.z * w2.z + t2.w * w2.w;
        a += t3.x * w3.x + t3.y * w3.y + t3.z * w3.z + t3.w * w3.w;
        ((float*)&ov)[qq] = (a > 20.f) ? a : log1pf(__expf(a));
    }
    *(float4*)(DT + (size_t)token * 512 + d0) = ov;
}

// ======== chunk-parallel selective scan (NC=4) ========
// pass 1: 1024 blocks (b, ch, c): scan CL=256 steps from h=0.
// c==0: finalize (u*D + silu(z) gate). c>0: raw partial y (bf16). Emit h_end, cumdt.
__global__ __launch_bounds__(256) void scan_part(const float* __restrict__ U,
                                                 const float* __restrict__ DBL,
                                                 const float* __restrict__ DT,
                                                 const float* __restrict__ XZ,
                                                 const float* __restrict__ A_log,
                                                 const float* __restrict__ Dp,
                                                 u16* __restrict__ YB,
                                                 float* __restrict__ HEND,
                                                 float* __restrict__ CUMDT) {
    __shared__ float s_dt[2][T_CH][16];
    __shared__ float s_u [2][T_CH][16];
    __shared__ float s_BC[2][T_CH][32];
    __shared__ float s_z [2][T_CH][16];
    __shared__ float s_y [2][T_CH * 17];

    int blk = blockIdx.x;                       // b(8) * ch(32) * c(4)
    int c = blk & 3, ch = (blk >> 2) & 31, b = blk >> 7;
    int tid = threadIdx.x;
    int s = tid & 15, dl = tid >> 4;
    int d = ch * 16 + dl;
    int w = tid >> 6;

    float Ads = -__expf(A_log[d * D_STATE + s]);
    float Dv = Dp[d];

    const float* DTb = DT  + (size_t)b * L_SEQ * D_INNER + ch * 16;
    const float* Ub  = U   + (size_t)b * L_SEQ * D_INNER + ch * 16;
    const float* DBb = DBL + (size_t)b * L_SEQ * 48 + 16;
    const float* Zb  = XZ  + (size_t)b * L_SEQ * 1024 + 512 + ch * 16;
    u16* Yb          = YB  + (size_t)b * L_SEQ * D_INNER + ch * 16;

    int r16 = tid >> 2, q16 = (tid & 3) << 2;
    int r32 = tid >> 3, q32 = (tid & 7) << 2;

    #define STAGE(t0a, bf) { \
        int t0_ = (t0a); \
        gload16(DTb + (size_t)(t0_ + r16) * 512 + q16, &s_dt[bf][0][0] + (w << 8)); \
        gload16(Ub  + (size_t)(t0_ + r16) * 512 + q16, &s_u [bf][0][0] + (w << 8)); \
        gload16(Zb  + (size_t)(t0_ + r16) * 1024 + q16, &s_z[bf][0][0] + (w << 8)); \
        gload16(DBb + (size_t)(t0_ + r32) * 48 + q32, &s_BC[bf][0][0] + (w << 8)); \
        gload16(DBb + (size_t)(t0_ + 32 + r32) * 48 + q32, &s_BC[bf][0][0] + 1024 + (w << 8)); \
    }

    float h = 0.f, cumdt = 0.f;
    int bf = 0;
    STAGE(c * CL, 0);
    __syncthreads();

    for (int cc = 0; cc < CL / T_CH; cc++) {
        if (cc + 1 < CL / T_CH) STAGE(c * CL + (cc + 1) * T_CH, bf ^ 1);
        int yb = cc & 1;
        #pragma unroll 1
        for (int tb = 0; tb < 4; tb++) {
            float da[16], db[16], cv[16], pr[16];
            float myud = 0.f;
            #pragma unroll
            for (int j = 0; j < 16; j++) {
                int t = (tb << 4) + j;
                float dtv = s_dt[bf][t][dl];
                float uv  = s_u [bf][t][dl];
                float bs  = s_BC[bf][t][s];
                float cs  = s_BC[bf][t][16 + s];
                cumdt += dtv;
                da[j] = __expf(dtv * Ads);
                db[j] = dtv * bs * uv;
                cv[j] = cs;
                myud = (s == j) ? uv * Dv : myud;
            }
            #pragma unroll
            for (int j = 0; j < 16; j++) {
                h = fmaf(da[j], h, db[j]);
                pr[j] = h * cv[j];
            }
            // transpose-reduce: lane s ends with the sum for t = tb*16+s
            float w8[8];
            #pragma unroll
            for (int k = 0; k < 8; k++) {
                float a = pr[2 * k], bv = pr[2 * k + 1];
                float keep = (s & 1) ? bv : a;
                float send = (s & 1) ? a : bv;
                w8[k] = keep + __shfl_xor(send, 1);
            }
            float u4[4];
            #pragma unroll
            for (int k = 0; k < 4; k++) {
                float a = w8[2 * k], bv = w8[2 * k + 1];
                float keep = (s & 2) ? bv : a;
                float send = (s & 2) ? a : bv;
                u4[k] = keep + __shfl_xor(send, 2);
            }
            float x2[2];
            #pragma unroll
            for (int k = 0; k < 2; k++) {
                float a = u4[2 * k], bv = u4[2 * k + 1];
                float keep = (s & 4) ? bv : a;
                float send = (s & 4) ? a : bv;
                x2[k] = keep + __shfl_xor(send, 4);
            }
            float a0 = x2[0], b0 = x2[1];
            float keep = (s & 8) ? b0 : a0;
            float send = (s & 8) ? a0 : b0;
            float res = keep + __shfl_xor(send, 8);
            int t = (tb << 4) + s;
            float y;
            if (c == 0) {
                float zv = s_z[bf][t][dl];
                y = (res + myud) * (zv / (1.f + __expf(-zv)));
            } else {
                y = res;   // raw partial; scan_fix finalizes
            }
            s_y[yb][t * 17 + dl] = y;
        }
        __syncthreads();
        {
            int t0_ = c * CL + cc * T_CH;
            int tt = tid >> 2, qq = (tid & 3) << 2;
            us4 o;
            o.x = f2b(s_y[yb][tt * 17 + qq + 0]);
            o.y = f2b(s_y[yb][tt * 17 + qq + 1]);
            o.z = f2b(s_y[yb][tt * 17 + qq + 2]);
            o.w = f2b(s_y[yb][tt * 17 + qq + 3]);
            *(us4*)(Yb + (size_t)(t0_ + tt) * 512 + qq) = o;
        }
        bf ^= 1;
    }
    #undef STAGE
    HEND[(((size_t)b * 4 + c) * 512 + d) * 16 + s] = h;
    if (s == 0) CUMDT[((size_t)b * 4 + c) * 512 + d] = cumdt;
}

// pass 2: h_init chains. 65536 threads, one (b,d,s) each.
__global__ __launch_bounds__(256) void scan_comb(const float* __restrict__ A_log,
                                                 const float* __restrict__ HEND,
                                                 const float* __restrict__ CUMDT,
                                                 float* __restrict__ HINIT) {
    int idx = blockIdx.x * 256 + threadIdx.x;   // 65536
    int s = idx & 15, d = (idx >> 4) & 511, b = idx >> 13;
    float As = -__expf(A_log[d * D_STATE + s]);
    float hi = HEND[(((size_t)b * 4 + 0) * 512 + d) * 16 + s];
    HINIT[(((size_t)b * 4 + 1) * 512 + d) * 16 + s] = hi;
    #pragma unroll
    for (int c = 2; c < 4; c++) {
        float cd = CUMDT[((size_t)b * 4 + (c - 1)) * 512 + d];
        float he = HEND[(((size_t)b * 4 + (c - 1)) * 512 + d) * 16 + s];
        hi = he + __expf(As * cd) * hi;
        HINIT[(((size_t)b * 4 + c) * 512 + d) * 16 + s] = hi;
    }
}

// pass 3: chunks 1..3: y += sum_s C_s * exp(A_s*cumdt) * h0_s; + u*D; gate; rewrite YB.
__global__ __launch_bounds__(256) void scan_fix(const float* __restrict__ U,
                                                const float* __restrict__ DBL,
                                                const float* __restrict__ DT,
                                                const float* __restrict__ XZ,
                                                const float* __restrict__ A_log,
                                                const float* __restrict__ Dp,
                                                const float* __restrict__ HINIT,
                                                u16* __restrict__ YB) {
    __shared__ float s_dt[2][T_CH][16];
    __shared__ float s_C [2][T_CH][16];
    __shared__ float s_u [2][T_CH][16];
    __shared__ float s_z [2][T_CH][16];
    __shared__ u16   s_yr[2][T_CH][16];
    __shared__ float s_y [2][T_CH * 17];

    int blk = blockIdx.x;                 // 768 = b(8) * ch(32) * 3
    int c = (blk % 3) + 1;
    int t3 = blk / 3;
    int ch = t3 & 31, b = t3 >> 5;
    int tid = threadIdx.x;
    int s = tid & 15, dl = tid >> 4;
    int d = ch * 16 + dl;
    int w = tid >> 6;

    float Ads = -__expf(A_log[d * D_STATE + s]);
    float Dv = Dp[d];
    float h0 = HINIT[(((size_t)b * 4 + c) * 512 + d) * 16 + s];

    const float* DTb = DT  + (size_t)b * L_SEQ * D_INNER + ch * 16;
    const float* Cb  = DBL + (size_t)b * L_SEQ * 48 + 32;
    const float* Ub  = U   + (size_t)b * L_SEQ * D_INNER + ch * 16;
    const float* Zb  = XZ  + (size_t)b * L_SEQ * 1024 + 512 + ch * 16;
    u16* Yb          = YB  + (size_t)b * L_SEQ * D_INNER + ch * 16;

    int r16 = tid >> 2, q16 = (tid & 3) << 2;
    int ry = (tid & 127) >> 1, qy = (tid & 1) << 3;   // bf16 y rows: 32B each, 2 lanes/row

    #define STAGEF(t0a, bf) { \
        int t0_ = (t0a); \
        gload16(DTb + (size_t)(t0_ + r16) * 512 + q16, &s_dt[bf][0][0] + (w << 8)); \
        gload16(Cb  + (size_t)(t0_ + r16) * 48 + q16, &s_C[bf][0][0] + (w << 8)); \
        gload16(Ub  + (size_t)(t0_ + r16) * 512 + q16, &s_u[bf][0][0] + (w << 8)); \
        gload16(Zb  + (size_t)(t0_ + r16) * 1024 + q16, &s_z[bf][0][0] + (w << 8)); \
        if (tid < 128) gload16(Yb + (size_t)(t0_ + ry) * 512 + qy, &s_yr[bf][0][0] + (w << 9)); \
    }

    float cumdt = 0.f;
    int bf = 0;
    STAGEF(c * CL, 0);
    __syncthreads();

    for (int cc = 0; cc < CL / T_CH; cc++) {
        if (cc + 1 < CL / T_CH) STAGEF(c * CL + (cc + 1) * T_CH, bf ^ 1);
        int yb = cc & 1;
        #pragma unroll 1
        for (int tb = 0; tb < 4; tb++) {
            float pr[16];
            float myud = 0.f;
            #pragma unroll
            for (int j = 0; j < 16; j++) {
                int t = (tb << 4) + j;
                float dtv = s_dt[bf][t][dl];
                cumdt += dtv;
                float cs = s_C[bf][t][s];
                pr[j] = __expf(Ads * cumdt) * cs * h0;
                myud = (s == j) ? s_u[bf][t][dl] * Dv : myud;
            }
            float w8[8];
            #pragma unroll
            for (int k = 0; k < 8; k++) {
                float a = pr[2 * k], bv = pr[2 * k + 1];
                float keep = (s & 1) ? bv : a;
                float send = (s & 1) ? a : bv;
                w8[k] = keep + __shfl_xor(send, 1);
            }
            float u4[4];
            #pragma unroll
            for (int k = 0; k < 4; k++) {
                float a = w8[2 * k], bv = w8[2 * k + 1];
                float keep = (s & 2) ? bv : a;
                float send = (s & 2) ? a : bv;
                u4[k] = keep + __shfl_xor(send, 2);
            }
            float x2[2];
            #pragma unroll
            for (int k = 0; k < 2; k++) {
                float a = u4[2 * k], bv = u4[2 * k + 1];
                float keep = (s & 4) ? bv : a;
                float send = (s & 4) ? a : bv;
                x2[k] = keep + __shfl_xor(send, 4);
            }
            float a0 = x2[0], b0 = x2[1];
            float keep = (s & 8) ? b0 : a0;
            float send = (s & 8) ? a0 : b0;
            float res = keep + __shfl_xor(send, 8);
            int t = (tb << 4) + s;
            float yrv = b2f(s_yr[bf][t][dl]);
            float zv = s_z[bf][t][dl];
            float y = yrv + res + myud;
            s_y[yb][t * 17 + dl] = y * (zv / (1.f + __expf(-zv)));
        }
        __syncthreads();
        {
            int t0_ = c * CL + cc * T_CH;
            int tt = tid >> 2, qq = (tid & 3) << 2;
            us4 o;
            o.x = f2b(s_y[yb][tt * 17 + qq + 0]);
            o.y = f2b(s_y[yb][tt * 17 + qq + 1]);
            o.z = f2b(s_y[yb][tt * 17 + qq + 2]);
            o.w = f2b(s_y[yb][tt * 17 + qq + 3]);
            *(us4*)(Yb + (size_t)(t0_ + tt) * 512 + qq) = o;
        }
        bf ^= 1;
    }
    #undef STAGEF
}

extern "C" void kernel_launch(void* const* d_in, const int* in_sizes, int n_in,
                              void* d_out, int out_size, void* d_ws, size_t ws_size,
                              hipStream_t stream) {
    (void)in_sizes; (void)n_in; (void)out_size; (void)ws_size;
    const float* x         = (const float*)d_in[0];
    const float* ln_g      = (const float*)d_in[1];
    const float* ln_b      = (const float*)d_in[2];
    const float* in_proj_w = (const float*)d_in[3];
    const float* conv_w    = (const float*)d_in[4];
    const float* conv_b    = (const float*)d_in[5];
    const float* x_proj_w  = (const float*)d_in[6];
    const float* dt_proj_w = (const float*)d_in[7];
    const float* dt_proj_b = (const float*)d_in[8];
    const float* A_log     = (const float*)d_in[9];
    const float* Dp        = (const float*)d_in[10];
    const float* out_proj_w= (const float*)d_in[11];
    const float* mlp_ln_g  = (const float*)d_in[12];
    const float* mlp_ln_b  = (const float*)d_in[13];
    const float* mlp_w1    = (const float*)d_in[14];
    const float* mlp_b1    = (const float*)d_in[15];
    const float* mlp_w2    = (const float*)d_in[16];
    const float* mlp_b2    = (const float*)d_in[17];

    float* ws  = (float*)d_ws;
    u16*   WB  = (u16*)(ws + OFF_WB);
    float* XT  = ws + OFF_XT;
    u16*   XNB = (u16*)(ws + OFF_XNB);
    float* XZ  = ws + OFF_XZ;
    float* XC  = ws + OFF_XC;
    float* DBL = ws + OFF_DBL;
    float* DT  = ws + OFF_DT;
    u16*   YB  = (u16*)(ws + OFF_YB);
    float* HE  = ws + OFF_HE;
    float* HI  = ws + OFF_HI;
    float* CD  = ws + OFF_CD;
    float* XF2 = ws + OFF_XF2;             // alias XC[0..2M)
    float* TOUT= ws + OFF_TOUT;            // alias XC[2M..4M)
    u16*   H   = (u16*)(ws + OFF_H);       // alias XZ[0..2M)
    float* out = (float*)d_out;

    // 0. weights -> bf16
    cvt5_kernel<<<3680, 256, 0, stream>>>(in_proj_w, out_proj_w, mlp_w1, mlp_w2, x_proj_w, WB);
    // 1. transpose x -> XT (token-major)
    tin_kernel<<<512, 256, 0, stream>>>(x, XT);
    // 2. LN1 -> XNB (bf16)
    ln_kernel<<<N_TOK, 256, 0, stream>>>(XT, ln_g, ln_b, XNB);
    // 3. in_proj: XZ = XNB @ W^T
    gemm_mfma<0><<<dim3(8, 64), 256, 0, stream>>>(XNB, WB + WB_IN, XZ, N_TOK, 1024, 256, nullptr, nullptr);
    // 4. conv + silu -> XC (fp32)
    conv_kernel<<<(N_TOK * D_INNER) / 256, 256, 0, stream>>>(XZ, conv_w, conv_b, XC);
    // 5. x_proj -> DBL
    xproj3_kernel<<<256, 128, 0, stream>>>(XC, WB + WB_XP, DBL);
    // 6. dt_proj + softplus -> DT
    dtproj_kernel<<<4096, 256, 0, stream>>>(DBL, dt_proj_w, dt_proj_b, DT);
    // 7-9. chunk-parallel selective scan -> YB (bf16)
    scan_part<<<1024, 256, 0, stream>>>(XC, DBL, DT, XZ, A_log, Dp, YB, HE, CD);
    scan_comb<<<256, 256, 0, stream>>>(A_log, HE, CD, HI);
    scan_fix<<<768, 256, 0, stream>>>(XC, DBL, DT, XZ, A_log, Dp, HI, YB);
    // 10. out_proj + residual(XT) -> XF2
    gemm_mfma<1><<<dim3(2, 64), 256, 0, stream>>>(YB, WB + WB_OUT, XF2, N_TOK, 256, 512, nullptr, XT);
    // 11. LN2 -> XNB
    ln_kernel<<<N_TOK, 256, 0, stream>>>(XF2, mlp_ln_g, mlp_ln_b, XNB);
    // 12. fc1 + bias + gelu -> H (bf16)
    gemm_mfma<2><<<dim3(8, 64), 256, 0, stream>>>(XNB, WB + WB_W1, H, N_TOK, 1024, 256, mlp_b1, nullptr);
    // 13. fc2 + b2 + residual(XF2) -> TOUT (token-major)
    gemm_mfma<3><<<dim3(2, 64), 256, 0, stream>>>(H, WB + WB_W2, TOUT, N_TOK, 256, 1024, mlp_b2, XF2);
    // 14. transpose TOUT -> d_out
    tout_kernel<<<512, 256, 0, stream>>>(TOUT, out);
}

// Round 11
// 329.023 us; speedup vs baseline: 1.0309x; 1.0309x over previous
//
#include <hip/hip_runtime.h>
#include <math.h>

#define DIM      256
#define L_SEQ    1024
#define B_SZ     8
#define D_INNER  512
#define D_STATE  16
#define DT_RANK  16
#define N_TOK    (B_SZ * L_SEQ)   // 8192
#define T_CH     64

typedef unsigned short u16;
typedef __attribute__((ext_vector_type(4))) float f32x4;
typedef __attribute__((ext_vector_type(8))) short short8;
struct __align__(8) us4 { u16 x, y, z, w; };

// ---- workspace float offsets (93.7 MB envelope; no overlapping live buffers) ----
#define OFF_WB   0                     // bf16 weights                  (  471,040)
#define OFF_XT   471040                // fp32 8192x256 token-major x   (2,097,152)
#define OFF_XNB  2568192               // bf16 8192x256 LN out          (1,048,576)
#define OFF_XZ   3616768               // bf16 8192x1024 xz             (4,194,304 fl used of 8,388,608)
#define OFF_XC   12005376              // bf16 8192x512 u (XCB)         (2,097,152 fl used of 4,194,304)
#define OFF_DBL  16199680              // fp32 8192x48                  (  393,216)
#define OFF_DT   16592896              // fp32 8192x512 dt              (4,194,304)
#define OFF_YB   20787200              // bf16 8192x512 y               (2,097,152)
// aliases onto dead regions:
#define OFF_XF2  OFF_XC                // XCB dead after scan
#define OFF_TOUT (OFF_XC + 2097152)
#define OFF_H    OFF_XZ                // XZB dead after scan
// WB sub-offsets in u16 elements
#define WB_IN    0
#define WB_OUT   262144
#define WB_W1    393216
#define WB_W2    655360
#define WB_XP    917504

__device__ __forceinline__ u16 f2b(float f) {
    unsigned int u = __float_as_uint(f);
    return (u16)((u + 0x7fffu + ((u >> 16) & 1u)) >> 16);   // RNE
}
__device__ __forceinline__ float b2f(u16 v) {
    return __uint_as_float(((unsigned)v) << 16);
}

// ---------------- weight fp32->bf16 convert (5 segments) ----------------
__global__ __launch_bounds__(256) void cvt5_kernel(const float* __restrict__ a,
                                                   const float* __restrict__ b,
                                                   const float* __restrict__ c,
                                                   const float* __restrict__ d,
                                                   const float* __restrict__ e,
                                                   u16* __restrict__ out) {
    int i = blockIdx.x * 256 + threadIdx.x;   // total 942080
    const float* src; int off;
    if (i < 262144)      { src = a; off = i; }
    else if (i < 393216) { src = b; off = i - 262144; }
    else if (i < 655360) { src = c; off = i - 393216; }
    else if (i < 917504) { src = d; off = i - 655360; }
    else                 { src = e; off = i - 917504; }
    out[i] = f2b(src[off]);
}

// ---------------- transpose in: x (8,256,1024) -> XT (8192,256) ----------------
__global__ __launch_bounds__(256) void tin_kernel(const float* __restrict__ x,
                                                  float* __restrict__ XT) {
    __shared__ float tile[64][65];
    int bb = blockIdx.x >> 6, c0 = ((blockIdx.x >> 4) & 3) << 6, l0 = (blockIdx.x & 15) << 6;
    int tr = threadIdx.x >> 6, tc = threadIdx.x & 63;
    const float* src = x + ((size_t)bb * 256 + c0) * 1024 + l0;
    #pragma unroll
    for (int i = 0; i < 16; i++) tile[tr + i * 4][tc] = src[(size_t)(tr + i * 4) * 1024 + tc];
    __syncthreads();
    float* dst = XT + ((size_t)bb * 1024 + l0) * 256 + c0;
    #pragma unroll
    for (int i = 0; i < 16; i++) dst[(size_t)(tr + i * 4) * 256 + tc] = tile[tc][tr + i * 4];
}

// ---------------- transpose out: TOUT (8192,256) -> out (8,256,1024) ----------------
__global__ __launch_bounds__(256) void tout_kernel(const float* __restrict__ T,
                                                   float* __restrict__ outp) {
    __shared__ float tile[64][65];
    int bb = blockIdx.x >> 6, c0 = ((blockIdx.x >> 4) & 3) << 6, l0 = (blockIdx.x & 15) << 6;
    int tr = threadIdx.x >> 6, tc = threadIdx.x & 63;
    const float* src = T + ((size_t)bb * 1024 + l0) * 256 + c0;
    #pragma unroll
    for (int i = 0; i < 16; i++) tile[tr + i * 4][tc] = src[(size_t)(tr + i * 4) * 256 + tc];
    __syncthreads();
    float* dst = outp + ((size_t)bb * 256 + c0) * 1024 + l0;
    #pragma unroll
    for (int i = 0; i < 16; i++) dst[(size_t)(tr + i * 4) * 1024 + tc] = tile[tc][tr + i * 4];
}

// ---------------- LayerNorm over C=256, one block per token; bf16 out ----------------
__global__ __launch_bounds__(256) void ln_kernel(const float* __restrict__ in,
                                                 const float* __restrict__ g,
                                                 const float* __restrict__ b,
                                                 u16* __restrict__ out) {
    int token = blockIdx.x;
    int c = threadIdx.x;
    float v = in[(size_t)token * DIM + c];
    float s = v, s2 = v * v;
    #pragma unroll
    for (int o = 32; o; o >>= 1) {
        s  += __shfl_down(s, o);
        s2 += __shfl_down(s2, o);
    }
    __shared__ float red[8];
    int w = threadIdx.x >> 6;
    if ((threadIdx.x & 63) == 0) { red[w] = s; red[4 + w] = s2; }
    __syncthreads();
    if (threadIdx.x == 0) {
        float a = 0.f, aa = 0.f;
        for (int i = 0; i < 4; i++) { a += red[i]; aa += red[4 + i]; }
        red[0] = a; red[4] = aa;
    }
    __syncthreads();
    float mean = red[0] * (1.f / DIM);
    float var  = red[4] * (1.f / DIM) - mean * mean;
    float rstd = rsqrtf(var + 1e-5f);
    out[(size_t)token * DIM + c] = f2b((v - mean) * rstd * g[c] + b[c]);
}

// ---------------- global->LDS async helper (16B) ----------------
__device__ __forceinline__ void gload16(const void* g, void* l) {
    __builtin_amdgcn_global_load_lds(
        (const __attribute__((address_space(1))) unsigned int*)g,
        (__attribute__((address_space(3))) unsigned int*)l,
        16, 0, 0);
}

// ---------------- bf16 MFMA GEMM: C[M,N] = A[M,K] @ W[N,K]^T ----------------
// EPI: 0 plain fp32; 1 fp32 + extra[m*DIM+n]; 2 bias+gelu bf16; 3 bias+extra fp32; 4 plain bf16
template <int EPI>
__global__ __launch_bounds__(256) void gemm_mfma(const u16* __restrict__ A,
                                                 const u16* __restrict__ W,
                                                 void* __restrict__ Cout,
                                                 int M, int N, int K,
                                                 const float* __restrict__ bias,
                                                 const float* __restrict__ extra) {
    __shared__ u16 Als[4096];   // [128][32] bf16
    __shared__ u16 Bls[4096];
    int tid = threadIdx.x;
    int w = tid >> 6, l = tid & 63;
    int m0 = blockIdx.y << 7, n0 = blockIdx.x << 7;

    int srow = tid >> 2;
    int scol = (tid & 3) << 3;
    const u16* Ag  = A + (size_t)(m0 + srow) * K + scol;
    const u16* Ag2 = A + (size_t)(m0 + 64 + srow) * K + scol;
    const u16* Wg  = W + (size_t)(n0 + srow) * K + scol;
    const u16* Wg2 = W + (size_t)(n0 + 64 + srow) * K + scol;
    u16* Ab0 = Als + (w << 9);
    u16* Ab1 = Als + 2048 + (w << 9);
    u16* Bb0 = Bls + (w << 9);
    u16* Bb1 = Bls + 2048 + (w << 9);

    int wr = (w >> 1) << 6, wc = (w & 1) << 6;
    int fr = l & 15, fk = (l >> 4) << 3;

    f32x4 acc[4][4] = {};
    for (int k0 = 0; k0 < K; k0 += 32) {
        gload16(Ag + k0, Ab0);
        gload16(Ag2 + k0, Ab1);
        gload16(Wg + k0, Bb0);
        gload16(Wg2 + k0, Bb1);
        __syncthreads();
        short8 af[4], bfr[4];
        #pragma unroll
        for (int i = 0; i < 4; i++)
            af[i] = *(const short8*)&Als[(wr + i * 16 + fr) * 32 + fk];
        #pragma unroll
        for (int j = 0; j < 4; j++)
            bfr[j] = *(const short8*)&Bls[(wc + j * 16 + fr) * 32 + fk];
        #pragma unroll
        for (int i = 0; i < 4; i++)
            #pragma unroll
            for (int j = 0; j < 4; j++)
                acc[i][j] = __builtin_amdgcn_mfma_f32_16x16x32_bf16(af[i], bfr[j], acc[i][j], 0, 0, 0);
        __syncthreads();
    }

    int cr = (l >> 4) << 2;
    int ccol = l & 15;
    #pragma unroll
    for (int i = 0; i < 4; i++) {
        #pragma unroll
        for (int j = 0; j < 4; j++) {
            int n = n0 + wc + j * 16 + ccol;
            #pragma unroll
            for (int r = 0; r < 4; r++) {
                int m = m0 + wr + i * 16 + cr + r;
                float v = acc[i][j][r];
                if (EPI == 0) {
                    ((float*)Cout)[(size_t)m * N + n] = v;
                } else if (EPI == 1) {
                    ((float*)Cout)[(size_t)m * N + n] = v + extra[(size_t)m * DIM + n];
                } else if (EPI == 2) {
                    v += bias[n];
                    ((u16*)Cout)[(size_t)m * N + n] = f2b(0.5f * v * (1.f + erff(v * 0.70710678118f)));
                } else if (EPI == 3) {
                    v += bias[n] + extra[(size_t)m * DIM + n];
                    ((float*)Cout)[(size_t)m * N + n] = v;
                } else {
                    ((u16*)Cout)[(size_t)m * N + n] = f2b(v);
                }
            }
        }
    }
}

// ---------------- depthwise causal conv (k=4) + silu; bf16 in, bf16 out, x4 vec ----------------
__global__ __launch_bounds__(256) void conv_kernel(const u16* __restrict__ XZB,
                                                   const float* __restrict__ cw,
                                                   const float* __restrict__ cb,
                                                   u16* __restrict__ XCB) {
    int idx = blockIdx.x * 256 + threadIdx.x;   // 1,048,576 total: (token, d4)
    int d4 = (idx & 127) << 2;
    int token = idx >> 7;
    int l = token & 1023, b = token >> 10;
    const u16* base = XZB + (size_t)b * L_SEQ * 1024 + d4;   // xi half cols [0,512)
    float4 bias4 = *(const float4*)(cb + d4);
    float acc0 = bias4.x, acc1 = bias4.y, acc2 = bias4.z, acc3 = bias4.w;
    #pragma unroll
    for (int j = 0; j < 4; j++) {
        int ls = l - 3 + j;
        if (ls >= 0) {
            us4 xv = *(const us4*)(base + (size_t)ls * 1024);
            acc0 = fmaf(b2f(xv.x), cw[(d4 + 0) * 4 + j], acc0);
            acc1 = fmaf(b2f(xv.y), cw[(d4 + 1) * 4 + j], acc1);
            acc2 = fmaf(b2f(xv.z), cw[(d4 + 2) * 4 + j], acc2);
            acc3 = fmaf(b2f(xv.w), cw[(d4 + 3) * 4 + j], acc3);
        }
    }
    us4 o;
    o.x = f2b(acc0 / (1.f + __expf(-acc0)));
    o.y = f2b(acc1 / (1.f + __expf(-acc1)));
    o.z = f2b(acc2 / (1.f + __expf(-acc2)));
    o.w = f2b(acc3 / (1.f + __expf(-acc3)));
    *(us4*)(XCB + (size_t)token * 512 + d4) = o;
}

// ---------------- xproj v3: MFMA x_proj from bf16 XCB, 256 blocks x 32 tokens ----------------
__global__ __launch_bounds__(128) void xproj3_kernel(const u16* __restrict__ XCB,
                                                     const u16* __restrict__ WXP,
                                                     float* __restrict__ DBL) {
    __shared__ float dbl_s[32][49];
    int tid = threadIdx.x;
    int w = tid >> 6, l = tid & 63;
    int m0 = blockIdx.x << 5;
    int fr = l & 15, fk = (l >> 4) << 3;
    const u16* Ab = XCB + (size_t)(m0 + (w << 4) + fr) * 512 + fk;
    const u16* Wb = WXP + (size_t)fr * 512 + fk;
    f32x4 acc[3] = {};
    for (int k0 = 0; k0 < 512; k0 += 32) {
        short8 a0 = *(const short8*)(Ab + k0);
        short8 b0 = *(const short8*)(Wb + k0);
        short8 b1 = *(const short8*)(Wb + 16 * 512 + k0);
        short8 b2 = *(const short8*)(Wb + 32 * 512 + k0);
        acc[0] = __builtin_amdgcn_mfma_f32_16x16x32_bf16(a0, b0, acc[0], 0, 0, 0);
        acc[1] = __builtin_amdgcn_mfma_f32_16x16x32_bf16(a0, b1, acc[1], 0, 0, 0);
        acc[2] = __builtin_amdgcn_mfma_f32_16x16x32_bf16(a0, b2, acc[2], 0, 0, 0);
    }
    int cr = (l >> 4) << 2, ccol = l & 15;
    #pragma unroll
    for (int j = 0; j < 3; j++)
        #pragma unroll
        for (int r = 0; r < 4; r++)
            dbl_s[(w << 4) + cr + r][j * 16 + ccol] = acc[j][r];
    __syncthreads();
    #pragma unroll
    for (int it = 0; it < 3; it++) {
        int fidx = it * 512 + tid * 4;
        int row = fidx / 48, col = fidx % 48;
        float4 v;
        v.x = dbl_s[row][col]; v.y = dbl_s[row][col + 1];
        v.z = dbl_s[row][col + 2]; v.w = dbl_s[row][col + 3];
        *(float4*)(DBL + (size_t)(m0 + row) * 48 + col) = v;
    }
}

// ---------------- dt_proj + softplus ----------------
__global__ __launch_bounds__(256) void dtproj_kernel(const float* __restrict__ DBL,
                                                     const float* __restrict__ wdt,
                                                     const float* __restrict__ wdb,
                                                     float* __restrict__ DT) {
    int idx = blockIdx.x * 256 + threadIdx.x;
    int token = idx >> 7, q = idx & 127;
    int d0 = q << 2;
    const float4* dtr4 = (const float4*)(DBL + (size_t)token * 48);
    float4 t0 = dtr4[0], t1 = dtr4[1], t2 = dtr4[2], t3 = dtr4[3];
    float4 ov;
    #pragma unroll
    for (int qq = 0; qq < 4; qq++) {
        int d = d0 + qq;
        const float4* wr = (const float4*)(wdt + (size_t)d * 16);
        float4 w0 = wr[0], w1 = wr[1], w2 = wr[2], w3 = wr[3];
        float a = wdb[d];
        a += t0.x * w0.x + t0.y * w0.y + t0.z * w0.z + t0.w * w0.w;
        a += t1.x * w1.x + t1.y * w1.y + t1.z * w1.z + t1.w * w1.w;
        a += t2.x * w2.x + t2.y * w2.y + t2.z * w2.z + t2.w * w2.w;
        a += t3.x * w3.x + t3.y * w3.y + t3.z * w3.z + t3.w * w3.w;
        ((float*)&ov)[qq] = (a > 20.f) ? a : log1pf(__expf(a));
    }
    *(float4*)(DT + (size_t)token * 512 + d0) = ov;
}

// ---------------- selective scan (single-pass, round-8 proven) + bf16 u/z staging ----------------
__global__ __launch_bounds__(256) void scan_kernel(const u16* __restrict__ U,
                                                   const float* __restrict__ DBL,
                                                   const float* __restrict__ DT,
                                                   const u16* __restrict__ XZB,
                                                   const float* __restrict__ A_log,
                                                   const float* __restrict__ Dp,
                                                   u16* __restrict__ YB) {
    __shared__ float s_dt[2][T_CH][16];
    __shared__ u16   s_u [2][T_CH][16];
    __shared__ float s_BC[2][T_CH][32];
    __shared__ u16   s_z [2][T_CH][16];
    __shared__ float s_y [2][T_CH * 17];   // padded stride 17

    int blk = blockIdx.x;
    int b = blk >> 5, ch = blk & 31;
    int tid = threadIdx.x;
    int s = tid & 15, dl = tid >> 4;
    int d = ch * 16 + dl;
    int w = tid >> 6;

    float Ads = -__expf(A_log[d * D_STATE + s]);
    float Dv = Dp[d];

    const float* DTb = DT  + (size_t)b * L_SEQ * D_INNER + ch * 16;
    const u16*   Ub  = U   + (size_t)b * L_SEQ * D_INNER + ch * 16;
    const float* DBb = DBL + (size_t)b * L_SEQ * 48 + 16;
    const u16*   Zb  = XZB + (size_t)b * L_SEQ * 1024 + 512 + ch * 16;
    u16* Yb          = YB  + (size_t)b * L_SEQ * D_INNER + ch * 16;

    int r16 = tid >> 2, q16 = (tid & 3) << 2;
    int r32 = tid >> 3, q32 = (tid & 7) << 2;
    // bf16 row staging: 64 rows x 16 u16 = 32B/row; waves 0,1 -> u, waves 2,3 -> z
    int rhb = (tid & 127) >> 1, qhb = (tid & 1) << 3;

    #define STAGE(c, bf) { \
        int t0_ = (c) * T_CH; \
        gload16(DTb + (size_t)(t0_ + r16) * 512 + q16, &s_dt[bf][0][0] + (w << 8)); \
        gload16(DBb + (size_t)(t0_ + r32) * 48 + q32, &s_BC[bf][0][0] + (w << 8)); \
        gload16(DBb + (size_t)(t0_ + 32 + r32) * 48 + q32, &s_BC[bf][0][0] + 1024 + (w << 8)); \
        if (tid < 128) { \
            gload16(Ub + (size_t)(t0_ + rhb) * 512 + qhb, (u16*)&s_u[bf][0][0] + ((w & 1) << 9)); \
        } else { \
            gload16(Zb + (size_t)(t0_ + rhb) * 1024 + qhb, (u16*)&s_z[bf][0][0] + ((w & 1) << 9)); \
        } \
    }

    float h = 0.f;
    int bf = 0;
    STAGE(0, 0);
    __syncthreads();

    for (int c = 0; c < L_SEQ / T_CH; c++) {
        if (c + 1 < L_SEQ / T_CH) STAGE(c + 1, bf ^ 1);
        int yb = c & 1;
        #pragma unroll 1
        for (int tb = 0; tb < 4; tb++) {
            float da[16], db[16], cc[16], pr[16];
            float myud = 0.f;
            #pragma unroll
            for (int j = 0; j < 16; j++) {
                int t = (tb << 4) + j;
                float dtv = s_dt[bf][t][dl];
                float uv  = b2f(s_u[bf][t][dl]);
                float bs  = s_BC[bf][t][s];
                float cs  = s_BC[bf][t][16 + s];
                da[j] = __expf(dtv * Ads);
                db[j] = dtv * bs * uv;
                cc[j] = cs;
                myud = (s == j) ? uv * Dv : myud;
            }
            #pragma unroll
            for (int j = 0; j < 16; j++) {
                h = fmaf(da[j], h, db[j]);
                pr[j] = h * cc[j];
            }
            // transpose-reduce: lane s ends with the sum for t = tb*16+s
            float w8[8];
            #pragma unroll
            for (int k = 0; k < 8; k++) {
                float a = pr[2 * k], bv = pr[2 * k + 1];
                float keep = (s & 1) ? bv : a;
                float send = (s & 1) ? a : bv;
                w8[k] = keep + __shfl_xor(send, 1);
            }
            float u4[4];
            #pragma unroll
            for (int k = 0; k < 4; k++) {
                float a = w8[2 * k], bv = w8[2 * k + 1];
                float keep = (s & 2) ? bv : a;
                float send = (s & 2) ? a : bv;
                u4[k] = keep + __shfl_xor(send, 2);
            }
            float x2[2];
            #pragma unroll
            for (int k = 0; k < 2; k++) {
                float a = u4[2 * k], bv = u4[2 * k + 1];
                float keep = (s & 4) ? bv : a;
                float send = (s & 4) ? a : bv;
                x2[k] = keep + __shfl_xor(send, 4);
            }
            float a0 = x2[0], b0 = x2[1];
            float keep = (s & 8) ? b0 : a0;
            float send = (s & 8) ? a0 : b0;
            float res = keep + __shfl_xor(send, 8);
            int t = (tb << 4) + s;
            float zv = b2f(s_z[bf][t][dl]);
            float y = res + myud;
            s_y[yb][t * 17 + dl] = y * (zv / (1.f + __expf(-zv)));
        }
        __syncthreads();
        {
            int t0_ = c * T_CH;
            int tt = tid >> 2, qq = (tid & 3) << 2;
            us4 o;
            o.x = f2b(s_y[yb][tt * 17 + qq + 0]);
            o.y = f2b(s_y[yb][tt * 17 + qq + 1]);
            o.z = f2b(s_y[yb][tt * 17 + qq + 2]);
            o.w = f2b(s_y[yb][tt * 17 + qq + 3]);
            *(us4*)(Yb + (size_t)(t0_ + tt) * 512 + qq) = o;
        }
        bf ^= 1;
    }
    #undef STAGE
}

extern "C" void kernel_launch(void* const* d_in, const int* in_sizes, int n_in,
                              void* d_out, int out_size, void* d_ws, size_t ws_size,
                              hipStream_t stream) {
    (void)in_sizes; (void)n_in; (void)out_size; (void)ws_size;
    const float* x         = (const float*)d_in[0];
    const float* ln_g      = (const float*)d_in[1];
    const float* ln_b      = (const float*)d_in[2];
    const float* in_proj_w = (const float*)d_in[3];
    const float* conv_w    = (const float*)d_in[4];
    const float* conv_b    = (const float*)d_in[5];
    const float* x_proj_w  = (const float*)d_in[6];
    const float* dt_proj_w = (const float*)d_in[7];
    const float* dt_proj_b = (const float*)d_in[8];
    const float* A_log     = (const float*)d_in[9];
    const float* Dp        = (const float*)d_in[10];
    const float* out_proj_w= (const float*)d_in[11];
    const float* mlp_ln_g  = (const float*)d_in[12];
    const float* mlp_ln_b  = (const float*)d_in[13];
    const float* mlp_w1    = (const float*)d_in[14];
    const float* mlp_b1    = (const float*)d_in[15];
    const float* mlp_w2    = (const float*)d_in[16];
    const float* mlp_b2    = (const float*)d_in[17];

    float* ws  = (float*)d_ws;
    u16*   WB  = (u16*)(ws + OFF_WB);
    float* XT  = ws + OFF_XT;
    u16*   XNB = (u16*)(ws + OFF_XNB);
    u16*   XZB = (u16*)(ws + OFF_XZ);      // bf16 xz
    u16*   XCB = (u16*)(ws + OFF_XC);      // bf16 u
    float* DBL = ws + OFF_DBL;
    float* DT  = ws + OFF_DT;
    u16*   YB  = (u16*)(ws + OFF_YB);
    float* XF2 = ws + OFF_XF2;             // alias XC region (dead after scan)
    float* TOUT= ws + OFF_TOUT;
    u16*   H   = (u16*)(ws + OFF_H);       // alias XZ region (dead after scan)
    float* out = (float*)d_out;

    // 0. weights -> bf16
    cvt5_kernel<<<3680, 256, 0, stream>>>(in_proj_w, out_proj_w, mlp_w1, mlp_w2, x_proj_w, WB);
    // 1. transpose x -> XT (token-major)
    tin_kernel<<<512, 256, 0, stream>>>(x, XT);
    // 2. LN1 -> XNB (bf16)
    ln_kernel<<<N_TOK, 256, 0, stream>>>(XT, ln_g, ln_b, XNB);
    // 3. in_proj: XZB (bf16) = XNB @ W^T
    gemm_mfma<4><<<dim3(8, 64), 256, 0, stream>>>(XNB, WB + WB_IN, XZB, N_TOK, 1024, 256, nullptr, nullptr);
    // 4. conv + silu -> XCB (bf16)
    conv_kernel<<<4096, 256, 0, stream>>>(XZB, conv_w, conv_b, XCB);
    // 5. x_proj -> DBL
    xproj3_kernel<<<256, 128, 0, stream>>>(XCB, WB + WB_XP, DBL);
    // 6. dt_proj + softplus -> DT
    dtproj_kernel<<<4096, 256, 0, stream>>>(DBL, dt_proj_w, dt_proj_b, DT);
    // 7. selective scan + *silu(z) -> YB (bf16)
    scan_kernel<<<256, 256, 0, stream>>>(XCB, DBL, DT, XZB, A_log, Dp, YB);
    // 8. out_proj + residual(XT) -> XF2
    gemm_mfma<1><<<dim3(2, 64), 256, 0, stream>>>(YB, WB + WB_OUT, XF2, N_TOK, 256, 512, nullptr, XT);
    // 9. LN2 -> XNB
    ln_kernel<<<N_TOK, 256, 0, stream>>>(XF2, mlp_ln_g, mlp_ln_b, XNB);
    // 10. fc1 + bias + gelu -> H (bf16)
    gemm_mfma<2><<<dim3(8, 64), 256, 0, stream>>>(XNB, WB + WB_W1, H, N_TOK, 1024, 256, mlp_b1, nullptr);
    // 11. fc2 + b2 + residual(XF2) -> TOUT (token-major)
    gemm_mfma<3><<<dim3(2, 64), 256, 0, stream>>>(H, WB + WB_W2, TOUT, N_TOK, 256, 1024, mlp_b2, XF2);
    // 12. transpose TOUT -> d_out
    tout_kernel<<<512, 256, 0, stream>>>(TOUT, out);
}